// Round 11
// baseline (118.588 us; speedup 1.0000x reference)
//
#include <hip/hip_runtime.h>
#include <stdint.h>

// Reference: X[256,256,32,32] f32 * mask, mask[b] = concat(ones(51ch),
// bernoulli(fold_in(key(101010), idx[b]), p=0.1, (205,32,32))).
// VERIFIED PRNG (r6/r8/r10 pass, absmax=0): 32-bit partitionable threefry,
//   elem i: (b1,b2) = threefry2x32(key, 0, i); word = b1 ^ b2;
//   keep iff (word >> 9) <= 838860  (== uniform < 0.1f exactly)
//   key = threefry2x32((0,101010),(0,idx[b]))
// idx layout: DETECTOR REQUIRED (r9 hardcoded int64 read FAILED while the
// detector-equivalent r10 PASSED -> the passthrough/int32 branch is live).
// Detection rule (validated r6/r8/r10): words 0..255 of the raw buffer;
// int64 iff ALL odd words are zero.
// Perf ladder: r6 132.3 (serial sum) -> r8 119.1 -> r10 116.9.
// Model: mem floor ~80us, VALU ~51us; r10 hides only half the VALU.
// r11: barrier-free preamble -- ballot-based detector + per-thread fold_in
// (no __shared__, no __syncthreads -> wave phases decorrelate, both pipes
// stay fed); per-quad store issued right after its mask.
// Geometry (floats): example stride 262144 = 65536 quads; fixed 13056 quads;
// quads at t, t+16384, t+32768, t+49152; 13056 < 16384 so quads 1-3 always
// mem-region; 13056 = 204*64 keeps the quad-0 branch wave-uniform.

#define EX_STRIDE    262144
#define FIXED_Q      13056
#define QUART_T      16384

typedef float f32x4 __attribute__((ext_vector_type(4)));

__device__ __forceinline__ uint32_t rotl32(uint32_t x, int d) {
    return (x << d) | (x >> (32 - d));
}

// JAX threefry2x32: 20 rounds, key injection every 4 rounds.
__device__ __forceinline__ void threefry2x32(uint32_t k0, uint32_t k1,
                                             uint32_t& x0, uint32_t& x1) {
    const uint32_t k2 = k0 ^ k1 ^ 0x1BD11BDAu;
    x0 += k0; x1 += k1;
#define TF_R(r) { x0 += x1; x1 = rotl32(x1, r); x1 ^= x0; }
    TF_R(13) TF_R(15) TF_R(26) TF_R(6)
    x0 += k1; x1 += k2 + 1u;
    TF_R(17) TF_R(29) TF_R(16) TF_R(24)
    x0 += k2; x1 += k0 + 2u;
    TF_R(13) TF_R(15) TF_R(26) TF_R(6)
    x0 += k0; x1 += k1 + 3u;
    TF_R(17) TF_R(29) TF_R(16) TF_R(24)
    x0 += k1; x1 += k2 + 4u;
    TF_R(13) TF_R(15) TF_R(26) TF_R(6)
    x0 += k2; x1 += k0 + 5u;
#undef TF_R
}

// Verified draw (byte-identical to r6/r8/r10): counts (0,i), word = b1^b2,
// keep iff (word>>9) <= 838860.
__device__ __forceinline__ float apply32(uint32_t k0, uint32_t k1,
                                         uint32_t i, float v) {
    uint32_t y0 = 0u, y1 = i;
    threefry2x32(k0, k1, y0, y1);
    return (((y0 ^ y1) >> 9) <= 838860u) ? v : 0.0f;
}

__device__ __forceinline__ void mask_quad(f32x4& v, uint32_t k0, uint32_t k1,
                                          uint32_t e) {
    v.x = apply32(k0, k1, e + 0u, v.x);
    v.y = apply32(k0, k1, e + 1u, v.y);
    v.z = apply32(k0, k1, e + 2u, v.z);
    v.w = apply32(k0, k1, e + 3u, v.w);
}

__global__ __launch_bounds__(256)
void tied_dropout_kernel(const float* __restrict__ X,
                         const int* __restrict__ idx_raw,
                         float* __restrict__ out) {
    const int b = blockIdx.y;
    const int lane = threadIdx.x & 63;

    // --- barrier-free idx-layout detection (same rule as r6/r8/r10) ---
    // Each lane inspects words lane*4 .. lane*4+3 (64 lanes cover all 256).
    // int64 layout <=> every odd word is zero.
    const int w1 = idx_raw[lane * 4 + 1];
    const int w3 = idx_raw[lane * 4 + 3];
    const unsigned long long ball = __ballot(w1 != 0 || w3 != 0);
    const bool is_i64 = (ball == 0ull);

    // --- fold_in(base_key=(0,101010), idx[b]) per-thread (wave-uniform) ---
    uint32_t f0 = 0u;
    uint32_t f1 = (uint32_t)(is_i64 ? idx_raw[2 * b] : idx_raw[b]);
    threefry2x32(0u, 101010u, f0, f1);
    const uint32_t k0 = f0, k1 = f1;

    const int t = blockIdx.x * blockDim.x + threadIdx.x;   // 0..16383

    const size_t ex_off = (size_t)b * EX_STRIDE;
    const f32x4* __restrict__ X4 = reinterpret_cast<const f32x4*>(X + ex_off);
    f32x4* __restrict__ O4 = reinterpret_cast<f32x4*>(out + ex_off);

    // Issue ALL FOUR loads up front (MLP); store each quad right after its
    // mask so stores spread through the hash burst.
    f32x4 v0 = __builtin_nontemporal_load(X4 + t);
    f32x4 v1 = __builtin_nontemporal_load(X4 + t + QUART_T);
    f32x4 v2 = __builtin_nontemporal_load(X4 + t + 2 * QUART_T);
    f32x4 v3 = __builtin_nontemporal_load(X4 + t + 3 * QUART_T);

    // Quad 0: fixed channels pass through; mem channels masked (wave-uniform).
    if (t >= FIXED_Q) {
        mask_quad(v0, k0, k1, (uint32_t)((t - FIXED_Q) << 2));
    }
    __builtin_nontemporal_store(v0, O4 + t);

    mask_quad(v1, k0, k1, (uint32_t)((t + 1 * QUART_T - FIXED_Q) << 2));
    __builtin_nontemporal_store(v1, O4 + t + QUART_T);

    mask_quad(v2, k0, k1, (uint32_t)((t + 2 * QUART_T - FIXED_Q) << 2));
    __builtin_nontemporal_store(v2, O4 + t + 2 * QUART_T);

    mask_quad(v3, k0, k1, (uint32_t)((t + 3 * QUART_T - FIXED_Q) << 2));
    __builtin_nontemporal_store(v3, O4 + t + 3 * QUART_T);
}

extern "C" void kernel_launch(void* const* d_in, const int* in_sizes, int n_in,
                              void* d_out, int out_size, void* d_ws, size_t ws_size,
                              hipStream_t stream) {
    const float* X = (const float*)d_in[0];
    const int* idx_raw = (const int*)d_in[1];
    // d_in[2] = epoch (ignored; reference applies mask unconditionally)
    float* out = (float*)d_out;

    dim3 block(256, 1, 1);
    dim3 grid(QUART_T / 256, 256, 1);     // (64, B=256)
    tied_dropout_kernel<<<grid, block, 0, stream>>>(X, idx_raw, out);
}

// Round 12
// 116.986 us; speedup vs baseline: 1.0137x; 1.0137x over previous
//
#include <hip/hip_runtime.h>
#include <stdint.h>

// Reference: X[256,256,32,32] f32 * mask, mask[b] = concat(ones(51ch),
// bernoulli(fold_in(key(101010), idx[b]), p=0.1, (205,32,32))).
// VERIFIED PRNG (r6/r8/r10/r11 pass, absmax=0): 32-bit partitionable threefry,
//   elem i: (b1,b2) = threefry2x32(key, 0, i); word = b1 ^ b2;
//   keep iff (word >> 9) <= 838860  (== uniform < 0.1f exactly)
//   key = threefry2x32((0,101010),(0,idx[b]))
// idx layout: DETECTOR REQUIRED (r9 hardcoded-int64 FAILED; detector forms
// r6/r8/r10/r11 all PASSED). Rule: words 0..255; int64 iff all odd words 0.
// Perf ladder: r6 132.3 -> r8 119.1 (2q+nt) -> r10 116.9 (4q, inline det)
//   -> r11 118.6 (ballot preamble, interleaved stores: neutral).
// r12 single-axis test (T7): REMOVE nt from loads (suspected L2 evict-first
// hurting streaming-read BW); keep nt stores, grouped at end (r10 placement);
// ballot preamble (no barriers).
// Geometry (floats): example stride 262144 = 65536 quads; fixed 13056 quads;
// quads at t, t+16384, t+32768, t+49152; 13056 < 16384 so quads 1-3 always
// mem-region; 13056 = 204*64 keeps the quad-0 branch wave-uniform.

#define EX_STRIDE    262144
#define FIXED_Q      13056
#define QUART_T      16384

typedef float f32x4 __attribute__((ext_vector_type(4)));

__device__ __forceinline__ uint32_t rotl32(uint32_t x, int d) {
    return (x << d) | (x >> (32 - d));
}

// JAX threefry2x32: 20 rounds, key injection every 4 rounds.
__device__ __forceinline__ void threefry2x32(uint32_t k0, uint32_t k1,
                                             uint32_t& x0, uint32_t& x1) {
    const uint32_t k2 = k0 ^ k1 ^ 0x1BD11BDAu;
    x0 += k0; x1 += k1;
#define TF_R(r) { x0 += x1; x1 = rotl32(x1, r); x1 ^= x0; }
    TF_R(13) TF_R(15) TF_R(26) TF_R(6)
    x0 += k1; x1 += k2 + 1u;
    TF_R(17) TF_R(29) TF_R(16) TF_R(24)
    x0 += k2; x1 += k0 + 2u;
    TF_R(13) TF_R(15) TF_R(26) TF_R(6)
    x0 += k0; x1 += k1 + 3u;
    TF_R(17) TF_R(29) TF_R(16) TF_R(24)
    x0 += k1; x1 += k2 + 4u;
    TF_R(13) TF_R(15) TF_R(26) TF_R(6)
    x0 += k2; x1 += k0 + 5u;
#undef TF_R
}

// Verified draw (byte-identical to r6/r8/r10/r11): counts (0,i),
// word = b1^b2, keep iff (word>>9) <= 838860.
__device__ __forceinline__ float apply32(uint32_t k0, uint32_t k1,
                                         uint32_t i, float v) {
    uint32_t y0 = 0u, y1 = i;
    threefry2x32(k0, k1, y0, y1);
    return (((y0 ^ y1) >> 9) <= 838860u) ? v : 0.0f;
}

__device__ __forceinline__ void mask_quad(f32x4& v, uint32_t k0, uint32_t k1,
                                          uint32_t e) {
    v.x = apply32(k0, k1, e + 0u, v.x);
    v.y = apply32(k0, k1, e + 1u, v.y);
    v.z = apply32(k0, k1, e + 2u, v.z);
    v.w = apply32(k0, k1, e + 3u, v.w);
}

__global__ __launch_bounds__(256)
void tied_dropout_kernel(const float* __restrict__ X,
                         const int* __restrict__ idx_raw,
                         float* __restrict__ out) {
    const int b = blockIdx.y;
    const int lane = threadIdx.x & 63;

    // --- barrier-free idx-layout detection (validated r11) ---
    // Each lane inspects words lane*4+1, lane*4+3 (64 lanes cover all 256).
    // int64 layout <=> every odd word is zero.
    const int w1 = idx_raw[lane * 4 + 1];
    const int w3 = idx_raw[lane * 4 + 3];
    const unsigned long long ball = __ballot(w1 != 0 || w3 != 0);
    const bool is_i64 = (ball == 0ull);

    // --- fold_in(base_key=(0,101010), idx[b]) per-thread (wave-uniform) ---
    uint32_t f0 = 0u;
    uint32_t f1 = (uint32_t)(is_i64 ? idx_raw[2 * b] : idx_raw[b]);
    threefry2x32(0u, 101010u, f0, f1);
    const uint32_t k0 = f0, k1 = f1;

    const int t = blockIdx.x * blockDim.x + threadIdx.x;   // 0..16383

    const size_t ex_off = (size_t)b * EX_STRIDE;
    const f32x4* __restrict__ X4 = reinterpret_cast<const f32x4*>(X + ex_off);
    f32x4* __restrict__ O4 = reinterpret_cast<f32x4*>(out + ex_off);

    // All 4 loads up front, PLAIN (no nt -- T7 test); hash; nt stores at end.
    f32x4 v0 = X4[t];
    f32x4 v1 = X4[t + QUART_T];
    f32x4 v2 = X4[t + 2 * QUART_T];
    f32x4 v3 = X4[t + 3 * QUART_T];

    // Quads 1-3 are always in the mem region (16384 > 13056).
    mask_quad(v1, k0, k1, (uint32_t)((t + 1 * QUART_T - FIXED_Q) << 2));
    mask_quad(v2, k0, k1, (uint32_t)((t + 2 * QUART_T - FIXED_Q) << 2));
    mask_quad(v3, k0, k1, (uint32_t)((t + 3 * QUART_T - FIXED_Q) << 2));

    // Quad 0: fixed channels pass through; mem channels masked (wave-uniform).
    if (t >= FIXED_Q) {
        mask_quad(v0, k0, k1, (uint32_t)((t - FIXED_Q) << 2));
    }

    __builtin_nontemporal_store(v0, O4 + t);
    __builtin_nontemporal_store(v1, O4 + t + QUART_T);
    __builtin_nontemporal_store(v2, O4 + t + 2 * QUART_T);
    __builtin_nontemporal_store(v3, O4 + t + 3 * QUART_T);
}

extern "C" void kernel_launch(void* const* d_in, const int* in_sizes, int n_in,
                              void* d_out, int out_size, void* d_ws, size_t ws_size,
                              hipStream_t stream) {
    const float* X = (const float*)d_in[0];
    const int* idx_raw = (const int*)d_in[1];
    // d_in[2] = epoch (ignored; reference applies mask unconditionally)
    float* out = (float*)d_out;

    dim3 block(256, 1, 1);
    dim3 grid(QUART_T / 256, 256, 1);     // (64, B=256)
    tied_dropout_kernel<<<grid, block, 0, stream>>>(X, idx_raw, out);
}

// Round 13
// 116.935 us; speedup vs baseline: 1.0141x; 1.0004x over previous
//
#include <hip/hip_runtime.h>
#include <stdint.h>

// Reference: X[256,256,32,32] f32 * mask, mask[b] = concat(ones(51ch),
// bernoulli(fold_in(key(101010), idx[b]), p=0.1, (205,32,32))).
// VERIFIED PRNG (r6/r8/r10/r11/r12 pass, absmax=0): 32-bit partitionable
// threefry: elem i: (b1,b2) = threefry2x32(key, 0, i); word = b1 ^ b2;
//   keep iff word < 429496832u   [PROVABLY == (word>>9) <= 838860: exact
//   integer form of uniform < 0.1f; 838861*512 = 429496832]
//   key = threefry2x32((0,101010),(0,idx[b]))
// idx layout: DETECTOR REQUIRED (r9 hardcoded-int64 FAILED; detector forms
// r6/r8/r10/r11/r12 all PASSED). Rule: words 0..255; int64 iff all odd 0.
// Perf ladder: r6 132.3 -> r8 119.1 -> r10 116.9 -> r11 118.6 -> r12 117.0.
// r12 PMC: FETCH 131MB (L3 absorbs half the input!), WRITE 262MB -> mem
// floor ~60-65us; VALUBusy-time ~93us -> VALU-BOUND (theory floor 51us).
// r13: cut VALU -- (1) rotl via __builtin_rotateleft32 (guarantee 1-inst
// v_alignbit); (2) keep-test without the >>9 (equal constant compare);
// (3) readfirstlane idx -> fold_in scalarizes to SALU pipe (parallel, free).
// Geometry: stride 262144 = 65536 quads/ex; fixed 13056 quads; quads at
// t, +16384, +32768, +49152; quads 1-3 always mem-region; 13056 = 204*64
// keeps the quad-0 branch wave-uniform.

#define EX_STRIDE    262144
#define FIXED_Q      13056
#define QUART_T      16384

typedef float f32x4 __attribute__((ext_vector_type(4)));

// JAX threefry2x32: 20 rounds, key injection every 4 rounds.
// rotl = __builtin_rotateleft32 -> fshl -> v_alignbit_b32 (1 VALU inst).
__device__ __forceinline__ void threefry2x32(uint32_t k0, uint32_t k1,
                                             uint32_t& x0, uint32_t& x1) {
    const uint32_t k2 = k0 ^ k1 ^ 0x1BD11BDAu;
    x0 += k0; x1 += k1;
#define TF_R(r) { x0 += x1; x1 = __builtin_rotateleft32(x1, r); x1 ^= x0; }
    TF_R(13) TF_R(15) TF_R(26) TF_R(6)
    x0 += k1; x1 += k2 + 1u;
    TF_R(17) TF_R(29) TF_R(16) TF_R(24)
    x0 += k2; x1 += k0 + 2u;
    TF_R(13) TF_R(15) TF_R(26) TF_R(6)
    x0 += k0; x1 += k1 + 3u;
    TF_R(17) TF_R(29) TF_R(16) TF_R(24)
    x0 += k1; x1 += k2 + 4u;
    TF_R(13) TF_R(15) TF_R(26) TF_R(6)
    x0 += k2; x1 += k0 + 5u;
#undef TF_R
}

// Verified draw: counts (0,i), word = b1^b2, keep iff word < 429496832u
// (identical predicate to the validated (word>>9) <= 838860).
__device__ __forceinline__ float apply32(uint32_t k0, uint32_t k1,
                                         uint32_t i, float v) {
    uint32_t y0 = 0u, y1 = i;
    threefry2x32(k0, k1, y0, y1);
    return ((y0 ^ y1) < 429496832u) ? v : 0.0f;
}

__device__ __forceinline__ void mask_quad(f32x4& v, uint32_t k0, uint32_t k1,
                                          uint32_t e) {
    v.x = apply32(k0, k1, e + 0u, v.x);
    v.y = apply32(k0, k1, e + 1u, v.y);
    v.z = apply32(k0, k1, e + 2u, v.z);
    v.w = apply32(k0, k1, e + 3u, v.w);
}

__global__ __launch_bounds__(256)
void tied_dropout_kernel(const float* __restrict__ X,
                         const int* __restrict__ idx_raw,
                         float* __restrict__ out) {
    const int b = blockIdx.y;
    const int lane = threadIdx.x & 63;

    // --- barrier-free idx-layout detection (validated r11/r12) ---
    // int64 layout <=> every odd 32-bit word of words 0..255 is zero.
    const int w1 = idx_raw[lane * 4 + 1];
    const int w3 = idx_raw[lane * 4 + 3];
    const unsigned long long ball = __ballot(w1 != 0 || w3 != 0);
    const bool is_i64 = (ball == 0ull);

    // --- fold_in(base_key=(0,101010), idx[b]) on the SALU pipe ---
    // readfirstlane makes the value provably uniform -> the whole threefry
    // chain scalarizes (s_add/s_xor/s_lshl...) and runs parallel to VALU.
    uint32_t raw_val = (uint32_t)(is_i64 ? idx_raw[2 * b] : idx_raw[b]);
    uint32_t f0 = 0u;
    uint32_t f1 = (uint32_t)__builtin_amdgcn_readfirstlane(raw_val);
    threefry2x32(0u, 101010u, f0, f1);
    const uint32_t k0 = f0, k1 = f1;

    const int t = blockIdx.x * blockDim.x + threadIdx.x;   // 0..16383

    const size_t ex_off = (size_t)b * EX_STRIDE;
    const f32x4* __restrict__ X4 = reinterpret_cast<const f32x4*>(X + ex_off);
    f32x4* __restrict__ O4 = reinterpret_cast<f32x4*>(out + ex_off);

    // All 4 loads up front (plain: L3-friendly reads); hash; nt stores.
    f32x4 v0 = X4[t];
    f32x4 v1 = X4[t + QUART_T];
    f32x4 v2 = X4[t + 2 * QUART_T];
    f32x4 v3 = X4[t + 3 * QUART_T];

    // Quads 1-3 are always in the mem region (16384 > 13056).
    mask_quad(v1, k0, k1, (uint32_t)((t + 1 * QUART_T - FIXED_Q) << 2));
    mask_quad(v2, k0, k1, (uint32_t)((t + 2 * QUART_T - FIXED_Q) << 2));
    mask_quad(v3, k0, k1, (uint32_t)((t + 3 * QUART_T - FIXED_Q) << 2));

    // Quad 0: fixed channels pass through; mem channels masked (wave-uniform).
    if (t >= FIXED_Q) {
        mask_quad(v0, k0, k1, (uint32_t)((t - FIXED_Q) << 2));
    }

    __builtin_nontemporal_store(v0, O4 + t);
    __builtin_nontemporal_store(v1, O4 + t + QUART_T);
    __builtin_nontemporal_store(v2, O4 + t + 2 * QUART_T);
    __builtin_nontemporal_store(v3, O4 + t + 3 * QUART_T);
}

extern "C" void kernel_launch(void* const* d_in, const int* in_sizes, int n_in,
                              void* d_out, int out_size, void* d_ws, size_t ws_size,
                              hipStream_t stream) {
    const float* X = (const float*)d_in[0];
    const int* idx_raw = (const int*)d_in[1];
    // d_in[2] = epoch (ignored; reference applies mask unconditionally)
    float* out = (float*)d_out;

    dim3 block(256, 1, 1);
    dim3 grid(QUART_T / 256, 256, 1);     // (64, B=256)
    tied_dropout_kernel<<<grid, block, 0, stream>>>(X, idx_raw, out);
}

// Round 14
// 116.118 us; speedup vs baseline: 1.0213x; 1.0070x over previous
//
#include <hip/hip_runtime.h>
#include <stdint.h>

// Reference: X[256,256,32,32] f32 * mask, mask[b] = concat(ones(51ch),
// bernoulli(fold_in(key(101010), idx[b]), p=0.1, (205,32,32))).
// VERIFIED PRNG (r6/r8/r10-r13 pass, absmax=0): 32-bit partitionable
// threefry: elem i: (b1,b2) = threefry2x32(key, 0, i); word = b1 ^ b2;
//   keep iff word < 429496832u (exact integer form of uniform < 0.1f)
//   key = threefry2x32((0,101010),(0,idx[b]))
// idx layout: DETECTOR REQUIRED (r9 hardcoded-int64 FAILED; detector forms
// all PASSED). Rule: words 0..255; int64 iff all odd words zero.
// Perf ladder: r6 132.3 -> r8 119.1 -> r10 116.9 -> r11 118.6 -> r12/r13 117.
// r13 PMC: VGPR=16 (!) -> compiler serialized all 16 hash chains/thread;
// dep-chain (add->alignbit->xor, ~4cy latency vs 2cy issue) leaves >=50%
// issue bubbles; VALUBusy 61% == inst x 4cy pipeline occupancy. FETCH=131MB
// (L3 absorbs half the reads) -> mem floor ~60us; VALU issue floor ~53us.
// r14: SOURCE-LEVEL 4-way lockstep interleave of the quad's hash chains
// (a,b,c,d advanced round-by-round) so one wave has 4 independent 3-inst
// groups per round; exact math per chain unchanged (init folds provably
// equal); launch_bounds(256,4) relaxes VGPR cap to 128.
// Geometry: stride 262144 = 65536 quads/ex; fixed 13056 quads; quads at
// t, +16384, +32768, +49152; quads 1-3 always mem-region; 13056 = 204*64
// keeps the quad-0 branch wave-uniform.

#define EX_STRIDE    262144
#define FIXED_Q      13056
#define QUART_T      16384

typedef float f32x4 __attribute__((ext_vector_type(4)));

// JAX threefry2x32 (scalar form, for fold_in): 20 rounds, inject every 4.
__device__ __forceinline__ void threefry2x32(uint32_t k0, uint32_t k1,
                                             uint32_t& x0, uint32_t& x1) {
    const uint32_t k2 = k0 ^ k1 ^ 0x1BD11BDAu;
    x0 += k0; x1 += k1;
#define TF_R(r) { x0 += x1; x1 = __builtin_rotateleft32(x1, r); x1 ^= x0; }
    TF_R(13) TF_R(15) TF_R(26) TF_R(6)
    x0 += k1; x1 += k2 + 1u;
    TF_R(17) TF_R(29) TF_R(16) TF_R(24)
    x0 += k2; x1 += k0 + 2u;
    TF_R(13) TF_R(15) TF_R(26) TF_R(6)
    x0 += k0; x1 += k1 + 3u;
    TF_R(17) TF_R(29) TF_R(16) TF_R(24)
    x0 += k1; x1 += k2 + 4u;
    TF_R(13) TF_R(15) TF_R(26) TF_R(6)
    x0 += k2; x1 += k0 + 5u;
#undef TF_R
}

// 4-way lockstep-interleaved threefry for one quad (elements e..e+3).
// Math per chain is operation-identical to the validated scalar form:
//   x0_init = 0 + k0;  x1_init = cnt + k1            (cnt = e + c)
//   round1: x0 += x1  ==>  a0 = k0 + a1  (folded)
//           x1 = rotl(x1_pre,13) ^ x0                (a1 still pre-round)
//   then rounds/injections exactly as scalar.
// Verified draw: word = x0^x1, keep iff word < 429496832u.
__device__ __forceinline__ void mask_quad4(f32x4& v, uint32_t k0, uint32_t k1,
                                           uint32_t k2, uint32_t e) {
    uint32_t a1 = e + k1;
    uint32_t b1 = a1 + 1u, c1 = a1 + 2u, d1 = a1 + 3u;
    uint32_t a0 = k0 + a1, b0 = k0 + b1, c0 = k0 + c1, d0 = k0 + d1;
    a1 = __builtin_rotateleft32(a1, 13) ^ a0;
    b1 = __builtin_rotateleft32(b1, 13) ^ b0;
    c1 = __builtin_rotateleft32(c1, 13) ^ c0;
    d1 = __builtin_rotateleft32(d1, 13) ^ d0;
#define R4(r) \
    a0 += a1; a1 = __builtin_rotateleft32(a1, r); a1 ^= a0; \
    b0 += b1; b1 = __builtin_rotateleft32(b1, r); b1 ^= b0; \
    c0 += c1; c1 = __builtin_rotateleft32(c1, r); c1 ^= c0; \
    d0 += d1; d1 = __builtin_rotateleft32(d1, r); d1 ^= d0;
#define I4(ka, kb) \
    a0 += (ka); a1 += (kb); b0 += (ka); b1 += (kb); \
    c0 += (ka); c1 += (kb); d0 += (ka); d1 += (kb);
    R4(15) R4(26) R4(6)
    I4(k1, k2 + 1u)
    R4(17) R4(29) R4(16) R4(24)
    I4(k2, k0 + 2u)
    R4(13) R4(15) R4(26) R4(6)
    I4(k0, k1 + 3u)
    R4(17) R4(29) R4(16) R4(24)
    I4(k1, k2 + 4u)
    R4(13) R4(15) R4(26) R4(6)
    I4(k2, k0 + 5u)
#undef R4
#undef I4
    v.x = ((a0 ^ a1) < 429496832u) ? v.x : 0.0f;
    v.y = ((b0 ^ b1) < 429496832u) ? v.y : 0.0f;
    v.z = ((c0 ^ c1) < 429496832u) ? v.z : 0.0f;
    v.w = ((d0 ^ d1) < 429496832u) ? v.w : 0.0f;
}

__global__ __launch_bounds__(256, 4)
void tied_dropout_kernel(const float* __restrict__ X,
                         const int* __restrict__ idx_raw,
                         float* __restrict__ out) {
    const int b = blockIdx.y;
    const int lane = threadIdx.x & 63;

    // --- barrier-free idx-layout detection (validated r11-r13) ---
    // int64 layout <=> every odd 32-bit word of words 0..255 is zero.
    const int w1 = idx_raw[lane * 4 + 1];
    const int w3 = idx_raw[lane * 4 + 3];
    const unsigned long long ball = __ballot(w1 != 0 || w3 != 0);
    const bool is_i64 = (ball == 0ull);

    // --- fold_in(base_key=(0,101010), idx[b]), SALU via readfirstlane ---
    uint32_t raw_val = (uint32_t)(is_i64 ? idx_raw[2 * b] : idx_raw[b]);
    uint32_t f0 = 0u;
    uint32_t f1 = (uint32_t)__builtin_amdgcn_readfirstlane(raw_val);
    threefry2x32(0u, 101010u, f0, f1);
    const uint32_t k0 = f0, k1 = f1;
    const uint32_t k2 = k0 ^ k1 ^ 0x1BD11BDAu;

    const int t = blockIdx.x * blockDim.x + threadIdx.x;   // 0..16383

    const size_t ex_off = (size_t)b * EX_STRIDE;
    const f32x4* __restrict__ X4 = reinterpret_cast<const f32x4*>(X + ex_off);
    f32x4* __restrict__ O4 = reinterpret_cast<f32x4*>(out + ex_off);

    // All 4 loads up front (plain reads: L3-friendly); hash; nt stores.
    f32x4 v0 = X4[t];
    f32x4 v1 = X4[t + QUART_T];
    f32x4 v2 = X4[t + 2 * QUART_T];
    f32x4 v3 = X4[t + 3 * QUART_T];

    // Quads 1-3 are always in the mem region (16384 > 13056).
    mask_quad4(v1, k0, k1, k2, (uint32_t)((t + 1 * QUART_T - FIXED_Q) << 2));
    mask_quad4(v2, k0, k1, k2, (uint32_t)((t + 2 * QUART_T - FIXED_Q) << 2));
    mask_quad4(v3, k0, k1, k2, (uint32_t)((t + 3 * QUART_T - FIXED_Q) << 2));

    // Quad 0: fixed channels pass through; mem channels masked (wave-uniform).
    if (t >= FIXED_Q) {
        mask_quad4(v0, k0, k1, k2, (uint32_t)((t - FIXED_Q) << 2));
    }

    __builtin_nontemporal_store(v0, O4 + t);
    __builtin_nontemporal_store(v1, O4 + t + QUART_T);
    __builtin_nontemporal_store(v2, O4 + t + 2 * QUART_T);
    __builtin_nontemporal_store(v3, O4 + t + 3 * QUART_T);
}

extern "C" void kernel_launch(void* const* d_in, const int* in_sizes, int n_in,
                              void* d_out, int out_size, void* d_ws, size_t ws_size,
                              hipStream_t stream) {
    const float* X = (const float*)d_in[0];
    const int* idx_raw = (const int*)d_in[1];
    // d_in[2] = epoch (ignored; reference applies mask unconditionally)
    float* out = (float*)d_out;

    dim3 block(256, 1, 1);
    dim3 grid(QUART_T / 256, 256, 1);     // (64, B=256)
    tied_dropout_kernel<<<grid, block, 0, stream>>>(X, idx_raw, out);
}